// Round 2
// baseline (681.961 us; speedup 1.0000x reference)
//
#include <hip/hip_runtime.h>

typedef unsigned short u16;
typedef __attribute__((ext_vector_type(8))) _Float16 f16x8;
typedef __attribute__((ext_vector_type(4))) float f32x4;
typedef __attribute__((ext_vector_type(4))) int i32x4;
typedef __attribute__((ext_vector_type(4))) unsigned short us4;

__device__ __forceinline__ u16 f2h(float f) {
  _Float16 h = (_Float16)f;
  return __builtin_bit_cast(unsigned short, h);
}
__device__ __forceinline__ float sigm(float v) { return 1.0f / (1.0f + __expf(-v)); }
__device__ __forceinline__ float tanh_(float v) {
  float t = __expf(-2.0f * fabsf(v));
  float r = (1.0f - t) / (1.0f + t);
  return v >= 0.0f ? r : -r;
}

// ---------------------------------------------------------------------------
// Weight swizzle: fp32 OIHW [512][512][3][3] x 4 gates -> fp16, laid out as
// [chgrp 32][chunk 16][k9 9][gch 64 = gate*16+chrow][ci 32]  (per set)
// so each conv block streams a fully contiguous 576 KB slice.
// Gate order: 0=i, 1=f, 2=o, 3=g(c).
// ---------------------------------------------------------------------------
__global__ void prep_weights(const float* __restrict__ wi, const float* __restrict__ wf,
                             const float* __restrict__ wo, const float* __restrict__ wc,
                             const float* __restrict__ ui, const float* __restrict__ uf,
                             const float* __restrict__ uo, const float* __restrict__ uc,
                             u16* __restrict__ dstW, u16* __restrict__ dstU) {
  int idx = blockIdx.x * 256 + threadIdx.x;       // uint index over both sets
  const int PERSET = 4718592;                     // 9.4M ushorts / 2
  int set = idx >= PERSET ? 1 : 0;
  int o = idx - set * PERSET;
  int j = o * 2;                                  // ushort index within set
  int ci = j & 31;
  int gch = (j >> 5) & 63;
  int t = j >> 11;                                // 0..4607
  int k9 = t % 9;
  int cc = t / 9;                                 // 0..511
  int chunk = cc & 15, chgrp = cc >> 4;
  int gate = gch >> 4, chrow = gch & 15;
  int ch = chgrp * 16 + chrow;
  int cin = chunk * 32 + ci;
  const float* s;
  if (set == 0) s = gate == 0 ? wi : gate == 1 ? wf : gate == 2 ? wo : wc;
  else          s = gate == 0 ? ui : gate == 1 ? uf : gate == 2 ? uo : uc;
  size_t si = (size_t)(ch * 512 + cin) * 9 + k9;
  unsigned int lo = f2h(s[si]);
  unsigned int hi = f2h(s[si + 9]);               // cin+1 -> +9 elements
  unsigned int* d = (unsigned int*)(set == 0 ? dstW : dstU);
  d[o] = lo | (hi << 16);
}

// ---------------------------------------------------------------------------
// M[p][t] = sum_e WQ[p*512+e][t] * WK[e]   (contracts the 134MB WQ once)
// ---------------------------------------------------------------------------
__global__ void wq_reduce(const float* __restrict__ WQ, const float* __restrict__ WK,
                          float* __restrict__ M) {
  __shared__ float wk[512];
  int t = threadIdx.x;
  wk[t] = WK[t];
  wk[t + 256] = WK[t + 256];
  __syncthreads();
  size_t p = blockIdx.x;
  const float* base = WQ + p * 131072 + t;
  float a = 0.f;
#pragma unroll 8
  for (int e = 0; e < 512; ++e) a = fmaf(base[(size_t)e * 256], wk[e], a);
  M[p * 256 + t] = a;
}

// ---------------------------------------------------------------------------
// scores[b,p] = txt2[b]·M[p]/sqrt(512); softmax over h (p = h*16+w);
// coef[b,p] = 1 + Wsum_b + (WV·Wsum_w)*attn     (A1 == 1 identically)
// ---------------------------------------------------------------------------
__global__ void attn_coef(const float* __restrict__ txt, const float* __restrict__ M,
                          const float* __restrict__ WV, const float* __restrict__ Wsum_w,
                          const float* __restrict__ Wsum_b, float* __restrict__ coef) {
  __shared__ float part[256];
  __shared__ float txts[2048];
  int tid = threadIdx.x;
  float ps = 0.f;
  for (int e = tid; e < 512; e += 256) ps += WV[e] * Wsum_w[e];
  part[tid] = ps;
  for (int i = tid; i < 2048; i += 256) txts[i] = txt[i];
  __syncthreads();
  if (tid == 0) {
    float s = 0.f;
    for (int i = 0; i < 256; ++i) s += part[i];
    part[0] = s;
  }
  __syncthreads();
  float s = part[0];
  float b0 = Wsum_b[0];
  if (tid < 128) {
    int b = tid >> 4, w = tid & 15;
    const float* tr = txts + b * 256;
    float sc[16], mx = -1e30f;
    for (int h = 0; h < 16; ++h) {
      const float* mr = M + (h * 16 + w) * 256;
      float d = 0.f;
      for (int e = 0; e < 256; ++e) d = fmaf(tr[e], mr[e], d);
      sc[h] = d * 0.044194173824159216f;  // 1/sqrt(512)
      mx = fmaxf(mx, sc[h]);
    }
    float den = 0.f;
    for (int h = 0; h < 16; ++h) { sc[h] = __expf(sc[h] - mx); den += sc[h]; }
    float inv = 1.0f / den;
    for (int h = 0; h < 16; ++h)
      coef[b * 256 + h * 16 + w] = 1.0f + b0 + s * sc[h] * inv;
  }
}

// ---------------------------------------------------------------------------
// AM = coef*x and H0 = x, both fp16 NHWC [b][p][ch] (staging-friendly).
// ---------------------------------------------------------------------------
__global__ void prep_inputs(const float* __restrict__ x, const float* __restrict__ coef,
                            u16* __restrict__ AM, u16* __restrict__ H0) {
  int idx = blockIdx.x * 256 + threadIdx.x;  // 0..1048575, == NHWC flat index
  int ch = idx & 511, p = (idx >> 9) & 255, b = idx >> 17;
  float xv = x[(size_t)(b * 512 + ch) * 256 + p];
  float cf = coef[b * 256 + p];
  AM[idx] = f2h(cf * xv);
  H0[idx] = f2h(xv);
}

// ---------------------------------------------------------------------------
// Fused 4-gate 3x3 conv as implicit GEMM (fp16 MFMA 16x16x32, fp32 acc).
// Grid: 256 blocks = [b 8][chgrp 32] (b = bidx>>5 so weight-sharing blocks
// land on the same XCD). Block: 256 thr = 4 waves; wave w owns rows y=4w..4w+3.
// M-tiles = gates (0:i 1:f 2:o 3:g), each 16 output channels (chgrp*16..+15).
// MODE 0: G = conv(AM,W*) + Wb + Ub  -> G ws (fragment layout, float4/lane)
// MODE 1: z = conv(h,U*) + G; LSTM update; write c (NCHW f32), h (NHWC fp16)
// MODE 2: same but final timestep: write d_out (NCHW f32) only.
// ---------------------------------------------------------------------------
template <int MODE>
__launch_bounds__(256, 2)
__global__ void conv4(const u16* __restrict__ in, const u16* __restrict__ wswz,
                      const float* __restrict__ bWi, const float* __restrict__ bUi,
                      const float* __restrict__ bWf, const float* __restrict__ bUf,
                      const float* __restrict__ bWo, const float* __restrict__ bUo,
                      const float* __restrict__ bWc, const float* __restrict__ bUc,
                      float* __restrict__ G, const float* __restrict__ c_src,
                      float* __restrict__ c_dst, u16* __restrict__ h_out,
                      float* __restrict__ out) {
  __shared__ __align__(16) u16 Alds[9 * 64 * 32];    // [k9][gch][ci]   36864 B
  __shared__ __align__(16) u16 Blds[18 * 18 * 32];   // [yy][xx][ci]    20736 B
  const int tid = threadIdx.x;
  const int b = blockIdx.x >> 5, chgrp = blockIdx.x & 31;
  const int wave = tid >> 6, lane = tid & 63;
  const int row = lane & 15, quad = lane >> 4;

  // Zero Blds once: zero-padded border persists across chunks.
  {
    i32x4 z = {0, 0, 0, 0};
    i32x4* bz = (i32x4*)Blds;
#pragma unroll
    for (int i = 0; i < 6; ++i) {
      int k = tid + 256 * i;
      if (k < 1296) bz[k] = z;
    }
  }

  f32x4 acc[4][4];
#pragma unroll
  for (int m = 0; m < 4; ++m)
#pragma unroll
    for (int n = 0; n < 4; ++n) acc[m][n] = (f32x4){0.f, 0.f, 0.f, 0.f};

  const u16* wsrc = wswz + (size_t)chgrp * 294912;
  const u16* isrc = in + (size_t)b * 131072;

  for (int chunk = 0; chunk < 16; ++chunk) {
    __syncthreads();
    // Stage weights: contiguous 36864 B -> Alds
    const i32x4* ws4 = (const i32x4*)(wsrc + chunk * 18432);
    i32x4* al4 = (i32x4*)Alds;
#pragma unroll
    for (int i = 0; i < 9; ++i) al4[tid + 256 * i] = ws4[tid + 256 * i];
    // Stage input chunk: NHWC rows (32 ci contiguous) -> padded [yy][xx][ci]
#pragma unroll
    for (int i = 0; i < 4; ++i) {
      int j = tid + 256 * i;
      int p = j >> 2, cq = j & 3;
      i32x4 v = *(const i32x4*)(isrc + p * 512 + chunk * 32 + cq * 8);
      *(i32x4*)(&Blds[((p >> 4) + 1) * 576 + ((p & 15) + 1) * 32 + cq * 8]) = v;
    }
    __syncthreads();
#pragma unroll
    for (int kx = 0; kx < 3; ++kx) {
      // B-fragments shared across ky: row index = y + ky = wave*4 + (n+ky)
      f16x8 bfr[6];
#pragma unroll
      for (int jj = 0; jj < 6; ++jj)
        bfr[jj] = *(const f16x8*)(&Blds[(wave * 4 + jj) * 576 + (row + kx) * 32 + quad * 8]);
#pragma unroll
      for (int ky = 0; ky < 3; ++ky) {
#pragma unroll
        for (int m = 0; m < 4; ++m) {
          f16x8 af = *(const f16x8*)(&Alds[((ky * 3 + kx) * 64 + m * 16 + row) * 32 + quad * 8]);
#pragma unroll
          for (int n = 0; n < 4; ++n)
            acc[m][n] = __builtin_amdgcn_mfma_f32_16x16x32_f16(af, bfr[n + ky], acc[m][n], 0, 0, 0);
        }
      }
    }
  }

  // ---- epilogue ----
  const int ch0 = chgrp * 16 + quad * 4;
  float* gptr = G + (((size_t)blockIdx.x * 4 + wave) * 16) * 256 + lane * 4;
  if constexpr (MODE == 0) {
#pragma unroll
    for (int m = 0; m < 4; ++m) {
      const float* bw = m == 0 ? bWi : m == 1 ? bWf : m == 2 ? bWo : bWc;
      const float* bu = m == 0 ? bUi : m == 1 ? bUf : m == 2 ? bUo : bUc;
      f32x4 bias;
#pragma unroll
      for (int r = 0; r < 4; ++r) bias[r] = bw[ch0 + r] + bu[ch0 + r];
#pragma unroll
      for (int n = 0; n < 4; ++n) {
        f32x4 v = acc[m][n] + bias;
        *(f32x4*)(gptr + (m * 4 + n) * 256) = v;
      }
    }
  } else {
#pragma unroll
    for (int n = 0; n < 4; ++n) {
      const int p = (wave * 4 + n) * 16 + row;
      f32x4 zi = acc[0][n] + *(const f32x4*)(gptr + (0 + n) * 256);
      f32x4 zf = acc[1][n] + *(const f32x4*)(gptr + (4 + n) * 256);
      f32x4 zo = acc[2][n] + *(const f32x4*)(gptr + (8 + n) * 256);
      f32x4 zg = acc[3][n] + *(const f32x4*)(gptr + (12 + n) * 256);
      f32x4 cold;
#pragma unroll
      for (int r = 0; r < 4; ++r)
        cold[r] = c_src[(size_t)(b * 512 + ch0 + r) * 256 + p];
      f32x4 cnew, hv;
#pragma unroll
      for (int r = 0; r < 4; ++r) {
        float iv = sigm(zi[r]);
        float fv = sigm(zf[r]);
        float ov = sigm(zo[r]);
        float gv = tanh_(zg[r]);
        float cn = fmaf(gv, iv, fv * cold[r]);
        cnew[r] = cn;
        hv[r] = tanh_(cn) * ov;
      }
      if constexpr (MODE == 1) {
#pragma unroll
        for (int r = 0; r < 4; ++r)
          c_dst[(size_t)(b * 512 + ch0 + r) * 256 + p] = cnew[r];
        us4 hb;
        hb[0] = f2h(hv[0]); hb[1] = f2h(hv[1]);
        hb[2] = f2h(hv[2]); hb[3] = f2h(hv[3]);
        *(us4*)(h_out + (size_t)b * 131072 + (size_t)p * 512 + ch0) = hb;
      } else {
#pragma unroll
        for (int r = 0; r < 4; ++r)
          out[(size_t)(b * 512 + ch0 + r) * 256 + p] = hv[r];
      }
    }
  }
}

extern "C" void kernel_launch(void* const* d_in, const int* in_sizes, int n_in,
                              void* d_out, int out_size, void* d_ws, size_t ws_size,
                              hipStream_t stream) {
  const float* x    = (const float*)d_in[0];
  const float* txt  = (const float*)d_in[1];
  const float* Wi_w = (const float*)d_in[7];
  const float* Wi_b = (const float*)d_in[8];
  const float* Ui_w = (const float*)d_in[9];
  const float* Ui_b = (const float*)d_in[10];
  const float* Wf_w = (const float*)d_in[11];
  const float* Wf_b = (const float*)d_in[12];
  const float* Uf_w = (const float*)d_in[13];
  const float* Uf_b = (const float*)d_in[14];
  const float* Wc_w = (const float*)d_in[15];
  const float* Wc_b = (const float*)d_in[16];
  const float* Uc_w = (const float*)d_in[17];
  const float* Uc_b = (const float*)d_in[18];
  const float* Wo_w = (const float*)d_in[19];
  const float* Wo_b = (const float*)d_in[20];
  const float* Uo_w = (const float*)d_in[21];
  const float* Uo_b = (const float*)d_in[22];
  const float* WQ   = (const float*)d_in[23];
  const float* WK   = (const float*)d_in[24];
  const float* WV   = (const float*)d_in[25];
  const float* Wsw  = (const float*)d_in[26];
  const float* Wsb  = (const float*)d_in[27];
  (void)in_sizes; (void)n_in; (void)ws_size;

  char* ws = (char*)d_ws;
  size_t off = 0;
  auto carve = [&](size_t n) {
    char* p = ws + off;
    off += (n + 255) & ~(size_t)255;
    return p;
  };
  u16* WswzW  = (u16*)carve(18874368);   // 4x512x512x9 fp16, swizzled
  u16* WswzU  = (u16*)carve(18874368);
  u16* AM     = (u16*)carve(2097152);    // fp16 NHWC
  u16* H0     = (u16*)carve(2097152);
  u16* H1     = (u16*)carve(2097152);
  float* G    = (float*)carve(16777216); // fragment-layout gate biases-from-AM
  float* C    = (float*)carve(4194304);  // cell state, NCHW f32
  float* M    = (float*)carve(262144);   // [256 p][256 t]
  float* coef = (float*)carve(8192);     // [8 b][256 p]

  prep_weights<<<36864, 256, 0, stream>>>(Wi_w, Wf_w, Wo_w, Wc_w,
                                          Ui_w, Uf_w, Uo_w, Uc_w, WswzW, WswzU);
  wq_reduce<<<256, 256, 0, stream>>>(WQ, WK, M);
  attn_coef<<<1, 256, 0, stream>>>(txt, M, WV, Wsw, Wsb, coef);
  prep_inputs<<<4096, 256, 0, stream>>>(x, coef, AM, H0);

  conv4<0><<<256, 256, 0, stream>>>(AM, WswzW, Wi_b, Ui_b, Wf_b, Uf_b,
                                    Wo_b, Uo_b, Wc_b, Uc_b,
                                    G, nullptr, nullptr, nullptr, nullptr);
  // 4 timesteps: h ping-pongs H0 <-> H1; c in-place; t=0 reads c from x.
  conv4<1><<<256, 256, 0, stream>>>(H0, WswzU, nullptr, nullptr, nullptr, nullptr,
                                    nullptr, nullptr, nullptr, nullptr,
                                    G, x, C, H1, nullptr);
  conv4<1><<<256, 256, 0, stream>>>(H1, WswzU, nullptr, nullptr, nullptr, nullptr,
                                    nullptr, nullptr, nullptr, nullptr,
                                    G, C, C, H0, nullptr);
  conv4<1><<<256, 256, 0, stream>>>(H0, WswzU, nullptr, nullptr, nullptr, nullptr,
                                    nullptr, nullptr, nullptr, nullptr,
                                    G, C, C, H1, nullptr);
  conv4<2><<<256, 256, 0, stream>>>(H1, WswzU, nullptr, nullptr, nullptr, nullptr,
                                    nullptr, nullptr, nullptr, nullptr,
                                    G, C, nullptr, nullptr, (float*)d_out);
}

// Round 3
// 555.814 us; speedup vs baseline: 1.2270x; 1.2270x over previous
//
#include <hip/hip_runtime.h>

typedef unsigned short u16;
typedef __attribute__((ext_vector_type(8))) _Float16 f16x8;
typedef __attribute__((ext_vector_type(4))) float f32x4;
typedef __attribute__((ext_vector_type(4))) int i32x4;
typedef __attribute__((ext_vector_type(4))) unsigned short us4;

__device__ __forceinline__ u16 f2h(float f) {
  _Float16 h = (_Float16)f;
  return __builtin_bit_cast(unsigned short, h);
}
__device__ __forceinline__ float sigm(float v) { return 1.0f / (1.0f + __expf(-v)); }
__device__ __forceinline__ float tanh_(float v) {
  float t = __expf(-2.0f * fabsf(v));
  float r = (1.0f - t) / (1.0f + t);
  return v >= 0.0f ? r : -r;
}

// async global->LDS DMA, 16 B per lane; LDS dest = wave-uniform base + lane*16
typedef const __attribute__((address_space(1))) unsigned int* gas_t;
typedef __attribute__((address_space(3))) unsigned int* las_t;
__device__ __forceinline__ void gl16(const u16* g, u16* l) {
  __builtin_amdgcn_global_load_lds((gas_t)g, (las_t)l, 16, 0, 0);
}

// ---------------------------------------------------------------------------
// prep_big: blocks 0..255 -> scores[b][p] (fused WQ contraction + txt dot);
//           block 0 also computes s = WV.Wsum_w and b0 -> sb[2]
//           blocks 256..37119 -> weight swizzle fp32 OIHW -> fp16
//           [chgrp 32][chunk 16][k9 9][gch 64][ci 32] per set (W then U).
// ---------------------------------------------------------------------------
__global__ void prep_big(const float* __restrict__ WQ, const float* __restrict__ WK,
                         const float* __restrict__ txt, const float* __restrict__ WV,
                         const float* __restrict__ Wsw, const float* __restrict__ Wsb,
                         const float* __restrict__ wi, const float* __restrict__ wf,
                         const float* __restrict__ wo, const float* __restrict__ wc,
                         const float* __restrict__ ui, const float* __restrict__ uf,
                         const float* __restrict__ uo, const float* __restrict__ uc,
                         u16* __restrict__ dstW, u16* __restrict__ dstU,
                         float* __restrict__ scores, float* __restrict__ sb) {
  __shared__ float wk[512];
  __shared__ float red[4];
  int tid = threadIdx.x;
  if (blockIdx.x < 256) {
    int lane = tid & 63, wave = tid >> 6;
    wk[tid] = WK[tid];
    wk[tid + 256] = WK[tid + 256];
    __syncthreads();
    size_t p = blockIdx.x;
    const float* base = WQ + p * 131072 + tid;
    float m = 0.f;
#pragma unroll 8
    for (int e = 0; e < 512; ++e) m = fmaf(base[(size_t)e * 256], wk[e], m);
    for (int b = 0; b < 8; ++b) {
      float v = m * txt[b * 256 + tid];
#pragma unroll
      for (int off = 32; off > 0; off >>= 1) v += __shfl_down(v, off, 64);
      if (lane == 0) red[wave] = v;
      __syncthreads();
      if (tid == 0)
        scores[b * 256 + p] = (red[0] + red[1] + red[2] + red[3]) * 0.044194173824159216f;
      __syncthreads();
    }
    if (blockIdx.x == 0) {
      float v = WV[tid] * Wsw[tid] + WV[tid + 256] * Wsw[tid + 256];
#pragma unroll
      for (int off = 32; off > 0; off >>= 1) v += __shfl_down(v, off, 64);
      if (lane == 0) red[wave] = v;
      __syncthreads();
      if (tid == 0) {
        sb[0] = red[0] + red[1] + red[2] + red[3];
        sb[1] = Wsb[0];
      }
    }
    return;
  }
  // ---- weight swizzle ----
  int idx = (blockIdx.x - 256) * 256 + tid;
  const int PERSET = 4718592;
  int set = idx >= PERSET ? 1 : 0;
  int o = idx - set * PERSET;
  int j = o * 2;
  int ci = j & 31;
  int gch = (j >> 5) & 63;
  int t = j >> 11;
  int k9 = t % 9;
  int cc = t / 9;
  int chunk = cc & 15, chgrp = cc >> 4;
  int gate = gch >> 4, chrow = gch & 15;
  int ch = chgrp * 16 + chrow;
  int cin = chunk * 32 + ci;
  const float* s;
  if (set == 0) s = gate == 0 ? wi : gate == 1 ? wf : gate == 2 ? wo : wc;
  else          s = gate == 0 ? ui : gate == 1 ? uf : gate == 2 ? uo : uc;
  size_t si = (size_t)(ch * 512 + cin) * 9 + k9;
  unsigned int lo = f2h(s[si]);
  unsigned int hi = f2h(s[si + 9]);
  unsigned int* d = (unsigned int*)(set == 0 ? dstW : dstU);
  d[o] = lo | (hi << 16);
}

// ---------------------------------------------------------------------------
// prep_inputs: coef computed inline from scores (softmax over h per (b,w));
// AM = coef*x, H0 = x, fp16 NHWC [b][p][ch].
// ---------------------------------------------------------------------------
__global__ void prep_inputs(const float* __restrict__ x, const float* __restrict__ scores,
                            const float* __restrict__ sb,
                            u16* __restrict__ AM, u16* __restrict__ H0) {
  int idx = blockIdx.x * 256 + threadIdx.x;  // NHWC flat index
  int ch = idx & 511, p = (idx >> 9) & 255, b = idx >> 17;
  int w = p & 15, h = p >> 4;
  float s = sb[0], b0 = sb[1];
  float mx = -1e30f;
#pragma unroll
  for (int hh = 0; hh < 16; ++hh) mx = fmaxf(mx, scores[b * 256 + hh * 16 + w]);
  float den = 0.f, my = 0.f;
#pragma unroll
  for (int hh = 0; hh < 16; ++hh) {
    float e = __expf(scores[b * 256 + hh * 16 + w] - mx);
    den += e;
    if (hh == h) my = e;
  }
  float coef = 1.0f + b0 + s * my / den;
  float xv = x[(size_t)(b * 512 + ch) * 256 + p];
  AM[idx] = f2h(coef * xv);
  H0[idx] = f2h(xv);
}

// ---------------------------------------------------------------------------
// Fused 4-gate 3x3 conv, implicit GEMM (fp16 MFMA 16x16x32, fp32 acc),
// double-buffered LDS + global_load_lds(16B) staging.
// Grid 256 = [b 8][chgrp 32]; 4 waves; wave w owns output rows y=4w..4w+3.
// MODE 0: timestep 0 fused: chunks 0-15 = W on AM (writes G=acc+biases at
//         k==15), chunks 16-31 = U on H0; LSTM with c_src=x.
// MODE 1: 16 chunks U on h; z = acc + G; LSTM; write c + h_out.
// MODE 2: final timestep: write d_out (NCHW f32) only.
// ---------------------------------------------------------------------------
template <int MODE>
__launch_bounds__(256, 1)
__global__ void conv4(const u16* __restrict__ inA, const u16* __restrict__ inH,
                      const u16* __restrict__ wW, const u16* __restrict__ wU,
                      const float* __restrict__ bWi, const float* __restrict__ bUi,
                      const float* __restrict__ bWf, const float* __restrict__ bUf,
                      const float* __restrict__ bWo, const float* __restrict__ bUo,
                      const float* __restrict__ bWc, const float* __restrict__ bUc,
                      float* __restrict__ G, const float* __restrict__ c_src,
                      float* __restrict__ c_dst, u16* __restrict__ h_out,
                      float* __restrict__ out) {
  __shared__ __align__(16) u16 Alds[2][9 * 64 * 32];   // 2x36864 B
  __shared__ __align__(16) u16 Blds[2][18 * 18 * 32];  // 2x20736 B
  const int tid = threadIdx.x;
  const int b = blockIdx.x >> 5, chgrp = blockIdx.x & 31;
  const int wave = tid >> 6, lane = tid & 63;
  const int row = lane & 15, quad = lane >> 4;
  const int NCH = (MODE == 0) ? 32 : 16;

  // Zero both B buffers once: zero border persists (DMA writes interior only).
  {
    i32x4 z = {0, 0, 0, 0};
    i32x4* bz = (i32x4*)Blds;
#pragma unroll
    for (int i = 0; i < 11; ++i) {
      int k = tid + 256 * i;
      if (k < 2592) bz[k] = z;
    }
  }

  const u16* wsrcW = (MODE == 0) ? wW + (size_t)chgrp * 294912 : nullptr;
  const u16* wsrcU = wU + (size_t)chgrp * 294912;
  const u16* isrcA = (MODE == 0) ? inA + (size_t)b * 131072 : nullptr;
  const u16* isrcH = inH + (size_t)b * 131072;

  auto stage = [&](int k, int buf) {
    const u16* gw;
    const u16* gi;
    if (MODE == 0 && k < 16) { gw = wsrcW + k * 18432; gi = isrcA + (k & 15) * 32; }
    else                     { gw = wsrcU + (k & 15) * 18432; gi = isrcH + (k & 15) * 32; }
    // weights: 9 wave-loads per wave (36864 B contiguous)
#pragma unroll
    for (int i = 0; i < 9; ++i)
      gl16(gw + (size_t)(i * 256 + tid) * 8, &Alds[buf][(i * 256 + (tid & 192)) * 8]);
    // input: 4 rows per wave; row y -> LDS row y+1, cols 1..16
#pragma unroll
    for (int j = 0; j < 4; ++j) {
      int y = j * 4 + wave;
      gl16(gi + (size_t)(y * 16 + (lane >> 2)) * 512 + (lane & 3) * 8,
           &Blds[buf][(y + 1) * 576 + 32]);
    }
  };

  f32x4 acc[4][4];
#pragma unroll
  for (int m = 0; m < 4; ++m)
#pragma unroll
    for (int n = 0; n < 4; ++n) acc[m][n] = (f32x4){0.f, 0.f, 0.f, 0.f};

  const int ch0 = chgrp * 16 + quad * 4;
  float* gptr = G + (((size_t)blockIdx.x * 4 + wave) * 16) * 256 + lane * 4;

  stage(0, 0);
  __syncthreads();

#pragma unroll 2
  for (int k = 0; k < NCH; ++k) {
    int cur = k & 1;
    if (k + 1 < NCH) stage(k + 1, cur ^ 1);
    const u16* A = Alds[cur];
    const u16* B = Blds[cur];
#pragma unroll
    for (int kx = 0; kx < 3; ++kx) {
      f16x8 bfr[6];
#pragma unroll
      for (int jj = 0; jj < 6; ++jj)
        bfr[jj] = *(const f16x8*)(&B[(wave * 4 + jj) * 576 + (row + kx) * 32 + quad * 8]);
#pragma unroll
      for (int ky = 0; ky < 3; ++ky) {
#pragma unroll
        for (int m = 0; m < 4; ++m) {
          f16x8 af = *(const f16x8*)(&A[((ky * 3 + kx) * 64 + m * 16 + row) * 32 + quad * 8]);
#pragma unroll
          for (int n = 0; n < 4; ++n)
            acc[m][n] = __builtin_amdgcn_mfma_f32_16x16x32_f16(af, bfr[n + ky], acc[m][n], 0, 0, 0);
        }
      }
    }
    if constexpr (MODE == 0) {
      if (k == 15) {  // W-half done: add biases, persist G = conv(AM,W)+bW+bU
#pragma unroll
        for (int m = 0; m < 4; ++m) {
          const float* bw = m == 0 ? bWi : m == 1 ? bWf : m == 2 ? bWo : bWc;
          const float* bu = m == 0 ? bUi : m == 1 ? bUf : m == 2 ? bUo : bUc;
          f32x4 bias;
#pragma unroll
          for (int r = 0; r < 4; ++r) bias[r] = bw[ch0 + r] + bu[ch0 + r];
#pragma unroll
          for (int n = 0; n < 4; ++n) {
            acc[m][n] = acc[m][n] + bias;
            *(f32x4*)(gptr + (m * 4 + n) * 256) = acc[m][n];
          }
        }
      }
    }
    __syncthreads();  // drains prefetch (vmcnt) + protects LDS reuse
  }

  // ---- epilogue: LSTM update ----
#pragma unroll
  for (int n = 0; n < 4; ++n) {
    const int p = (wave * 4 + n) * 16 + row;
    f32x4 zi = acc[0][n], zf = acc[1][n], zo = acc[2][n], zg = acc[3][n];
    if constexpr (MODE != 0) {
      zi = zi + *(const f32x4*)(gptr + (0 + n) * 256);
      zf = zf + *(const f32x4*)(gptr + (4 + n) * 256);
      zo = zo + *(const f32x4*)(gptr + (8 + n) * 256);
      zg = zg + *(const f32x4*)(gptr + (12 + n) * 256);
    }
    f32x4 cold;
#pragma unroll
    for (int r = 0; r < 4; ++r)
      cold[r] = c_src[(size_t)(b * 512 + ch0 + r) * 256 + p];
    f32x4 cnew, hv;
#pragma unroll
    for (int r = 0; r < 4; ++r) {
      float iv = sigm(zi[r]);
      float fv = sigm(zf[r]);
      float ov = sigm(zo[r]);
      float gv = tanh_(zg[r]);
      float cn = fmaf(gv, iv, fv * cold[r]);
      cnew[r] = cn;
      hv[r] = tanh_(cn) * ov;
    }
    if constexpr (MODE != 2) {
#pragma unroll
      for (int r = 0; r < 4; ++r)
        c_dst[(size_t)(b * 512 + ch0 + r) * 256 + p] = cnew[r];
      us4 hb;
      hb[0] = f2h(hv[0]); hb[1] = f2h(hv[1]);
      hb[2] = f2h(hv[2]); hb[3] = f2h(hv[3]);
      *(us4*)(h_out + (size_t)b * 131072 + (size_t)p * 512 + ch0) = hb;
    } else {
#pragma unroll
      for (int r = 0; r < 4; ++r)
        out[(size_t)(b * 512 + ch0 + r) * 256 + p] = hv[r];
    }
  }
}

extern "C" void kernel_launch(void* const* d_in, const int* in_sizes, int n_in,
                              void* d_out, int out_size, void* d_ws, size_t ws_size,
                              hipStream_t stream) {
  const float* x    = (const float*)d_in[0];
  const float* txt  = (const float*)d_in[1];
  const float* Wi_w = (const float*)d_in[7];
  const float* Wi_b = (const float*)d_in[8];
  const float* Ui_w = (const float*)d_in[9];
  const float* Ui_b = (const float*)d_in[10];
  const float* Wf_w = (const float*)d_in[11];
  const float* Wf_b = (const float*)d_in[12];
  const float* Uf_w = (const float*)d_in[13];
  const float* Uf_b = (const float*)d_in[14];
  const float* Wc_w = (const float*)d_in[15];
  const float* Wc_b = (const float*)d_in[16];
  const float* Uc_w = (const float*)d_in[17];
  const float* Uc_b = (const float*)d_in[18];
  const float* Wo_w = (const float*)d_in[19];
  const float* Wo_b = (const float*)d_in[20];
  const float* Uo_w = (const float*)d_in[21];
  const float* Uo_b = (const float*)d_in[22];
  const float* WQ   = (const float*)d_in[23];
  const float* WK   = (const float*)d_in[24];
  const float* WV   = (const float*)d_in[25];
  const float* Wsw  = (const float*)d_in[26];
  const float* Wsb  = (const float*)d_in[27];
  (void)in_sizes; (void)n_in; (void)ws_size;

  char* ws = (char*)d_ws;
  size_t off = 0;
  auto carve = [&](size_t n) {
    char* p = ws + off;
    off += (n + 255) & ~(size_t)255;
    return p;
  };
  u16* WswzW    = (u16*)carve(18874368);   // 4x512x512x9 fp16, swizzled
  u16* WswzU    = (u16*)carve(18874368);
  u16* AM       = (u16*)carve(2097152);    // fp16 NHWC
  u16* H0       = (u16*)carve(2097152);
  u16* H1       = (u16*)carve(2097152);
  float* G      = (float*)carve(16777216); // fragment-layout W-conv + biases
  float* C      = (float*)carve(4194304);  // cell state, NCHW f32
  float* scores = (float*)carve(8192);     // [8 b][256 p]
  float* sb     = (float*)carve(256);      // s, b0

  prep_big<<<37120, 256, 0, stream>>>(WQ, WK, txt, WV, Wsw, Wsb,
                                      Wi_w, Wf_w, Wo_w, Wc_w,
                                      Ui_w, Uf_w, Uo_w, Uc_w,
                                      WswzW, WswzU, scores, sb);
  prep_inputs<<<4096, 256, 0, stream>>>(x, scores, sb, AM, H0);

  // t=0 fused (W on AM + U on H0), then 3 more timesteps ping-ponging h.
  conv4<0><<<256, 256, 0, stream>>>(AM, H0, WswzW, WswzU,
                                    Wi_b, Ui_b, Wf_b, Uf_b, Wo_b, Uo_b, Wc_b, Uc_b,
                                    G, x, C, H1, nullptr);
  conv4<1><<<256, 256, 0, stream>>>(nullptr, H1, nullptr, WswzU,
                                    nullptr, nullptr, nullptr, nullptr,
                                    nullptr, nullptr, nullptr, nullptr,
                                    G, C, C, H0, nullptr);
  conv4<1><<<256, 256, 0, stream>>>(nullptr, H0, nullptr, WswzU,
                                    nullptr, nullptr, nullptr, nullptr,
                                    nullptr, nullptr, nullptr, nullptr,
                                    G, C, C, H1, nullptr);
  conv4<2><<<256, 256, 0, stream>>>(nullptr, H1, nullptr, WswzU,
                                    nullptr, nullptr, nullptr, nullptr,
                                    nullptr, nullptr, nullptr, nullptr,
                                    G, C, nullptr, nullptr, (float*)d_out);
}

// Round 4
// 525.415 us; speedup vs baseline: 1.2979x; 1.0579x over previous
//
#include <hip/hip_runtime.h>

typedef unsigned short u16;
typedef __attribute__((ext_vector_type(8))) _Float16 f16x8;
typedef __attribute__((ext_vector_type(4))) float f32x4;
typedef __attribute__((ext_vector_type(4))) int i32x4;
typedef __attribute__((ext_vector_type(4))) unsigned short us4;

__device__ __forceinline__ u16 f2h(float f) {
  _Float16 h = (_Float16)f;
  return __builtin_bit_cast(unsigned short, h);
}
__device__ __forceinline__ float sigm(float v) { return 1.0f / (1.0f + __expf(-v)); }
__device__ __forceinline__ float tanh_(float v) {
  float t = __expf(-2.0f * fabsf(v));
  float r = (1.0f - t) / (1.0f + t);
  return v >= 0.0f ? r : -r;
}

// async global->LDS DMA, 16 B per lane; LDS dest = wave-uniform base + lane*16
typedef const __attribute__((address_space(1))) unsigned int* gas_t;
typedef __attribute__((address_space(3))) unsigned int* las_t;
__device__ __forceinline__ void gl16(const u16* g, u16* l) {
  __builtin_amdgcn_global_load_lds((gas_t)g, (las_t)l, 16, 0, 0);
}

// ---------------------------------------------------------------------------
// prep_big:
//  blocks 0..2047   = [es 8][p 256]: partial scores[b][p] += (Sum_t Sum_e-slice
//                     WQ[p*512+e][t]*WK[e]*txt[b][t]) / sqrt(512)  (atomicAdd;
//                     scores pre-zeroed by a memset node). Block 0 also -> sb.
//  blocks 2048..3071 = [set 2][chgrp 32][chunk 16] weight swizzle via LDS:
//                     coalesced contiguous 288-float strips in, contiguous
//                     36864 B swizzled [k9][gch 64][ci 32] slice out.
// ---------------------------------------------------------------------------
__global__ void prep_big(const float* __restrict__ WQ, const float* __restrict__ WK,
                         const float* __restrict__ txt, const float* __restrict__ WV,
                         const float* __restrict__ Wsw, const float* __restrict__ Wsb,
                         const float* __restrict__ wi, const float* __restrict__ wf,
                         const float* __restrict__ wo, const float* __restrict__ wc,
                         const float* __restrict__ ui, const float* __restrict__ uf,
                         const float* __restrict__ uo, const float* __restrict__ uc,
                         u16* __restrict__ dstW, u16* __restrict__ dstU,
                         float* __restrict__ scores, float* __restrict__ sb) {
  __shared__ __align__(16) u16 L[9 * 64 * 32];   // swizzle staging (36864 B)
  __shared__ float wk[64];
  __shared__ float red[4];
  int tid = threadIdx.x;
  if (blockIdx.x < 2048) {
    int p = blockIdx.x & 255;
    int es = blockIdx.x >> 8;                    // e-slice 0..7
    if (tid < 64) wk[tid] = WK[es * 64 + tid];
    __syncthreads();
    const float* base = WQ + (size_t)p * 131072 + (size_t)es * 16384 + tid;
    float m = 0.f;
#pragma unroll 8
    for (int e = 0; e < 64; ++e) m = fmaf(base[(size_t)e * 256], wk[e], m);
    int lane = tid & 63, wave = tid >> 6;
    for (int b = 0; b < 8; ++b) {
      float v = m * txt[b * 256 + tid];
#pragma unroll
      for (int off = 32; off; off >>= 1) v += __shfl_down(v, off, 64);
      if (lane == 0) red[wave] = v;
      __syncthreads();
      if (tid == 0)
        atomicAdd(&scores[b * 256 + p],
                  (red[0] + red[1] + red[2] + red[3]) * 0.044194173824159216f);
      __syncthreads();
    }
    if (blockIdx.x == 0) {
      float v = WV[tid] * Wsw[tid] + WV[tid + 256] * Wsw[tid + 256];
#pragma unroll
      for (int off = 32; off; off >>= 1) v += __shfl_down(v, off, 64);
      if (lane == 0) red[wave] = v;
      __syncthreads();
      if (tid == 0) {
        sb[0] = red[0] + red[1] + red[2] + red[3];
        sb[1] = Wsb[0];
      }
    }
    return;
  }
  // ---- weight swizzle ----
  int sbid = blockIdx.x - 2048;                  // 0..1023
  int set = sbid >> 9;
  int chgrp = (sbid >> 4) & 31;
  int chunk = sbid & 15;
  int q = tid & 3, gch = tid >> 2;               // 4 threads per (gate,chrow)
  int gate = gch >> 4, chrow = gch & 15;
  int ch = chgrp * 16 + chrow;
  const float* s;
  if (set == 0) s = gate == 0 ? wi : gate == 1 ? wf : gate == 2 ? wo : wc;
  else          s = gate == 0 ? ui : gate == 1 ? uf : gate == 2 ? uo : uc;
  const float* strip = s + (size_t)(ch * 512 + chunk * 32) * 9;  // 288 contiguous
#pragma unroll
  for (int c8 = 0; c8 < 8; ++c8) {
    int cl = q * 8 + c8;
#pragma unroll
    for (int k9 = 0; k9 < 9; ++k9)
      L[(k9 * 64 + gch) * 32 + cl] = f2h(strip[cl * 9 + k9]);
  }
  __syncthreads();
  u16* dst = (set == 0 ? dstW : dstU) + (size_t)(chgrp * 16 + chunk) * 18432;
  i32x4* d4 = (i32x4*)dst;
  i32x4* l4 = (i32x4*)L;
#pragma unroll
  for (int i = 0; i < 9; ++i) d4[i * 256 + tid] = l4[i * 256 + tid];
}

// ---------------------------------------------------------------------------
// prep_inputs: coef from scores (softmax over h per (b,w)); AM = coef*x,
// H0 = x, fp16 NHWC [b][p][ch].
// ---------------------------------------------------------------------------
__global__ void prep_inputs(const float* __restrict__ x, const float* __restrict__ scores,
                            const float* __restrict__ sb,
                            u16* __restrict__ AM, u16* __restrict__ H0) {
  int idx = blockIdx.x * 256 + threadIdx.x;  // NHWC flat index
  int ch = idx & 511, p = (idx >> 9) & 255, b = idx >> 17;
  int w = p & 15, h = p >> 4;
  float s = sb[0], b0 = sb[1];
  float mx = -1e30f;
#pragma unroll
  for (int hh = 0; hh < 16; ++hh) mx = fmaxf(mx, scores[b * 256 + hh * 16 + w]);
  float den = 0.f, my = 0.f;
#pragma unroll
  for (int hh = 0; hh < 16; ++hh) {
    float e = __expf(scores[b * 256 + hh * 16 + w] - mx);
    den += e;
    if (hh == h) my = e;
  }
  float coef = 1.0f + b0 + s * my / den;
  float xv = x[(size_t)(b * 512 + ch) * 256 + p];
  AM[idx] = f2h(coef * xv);
  H0[idx] = f2h(xv);
}

// ---------------------------------------------------------------------------
// Fused 4-gate 3x3 conv, implicit GEMM (fp16 MFMA 16x16x32, fp32 acc).
// Grid 512 = [b 8][nhalf 2][chgrp 32] (chgrp low bits -> weight-sharing
// blocks on same XCD). Each block: M=64 (4 gates x 16 ch), N=128 (8 position
// rows), K = 16 chunks x 288. Single-buffered LDS (48.4 KB -> 2 blocks/CU,
// 2 waves/SIMD), m97 2-barrier K-loop with global_load_lds(16B) staging.
// Wave w owns local output rows 2w, 2w+1 -> acc[4][2], 4 B-fragments.
// MODE 0: chunks 0-15 = W on AM (G=acc+biases stored at k==15), 16-31 = U on
//         H0; LSTM with c_src=x.   MODE 1: U on h; z=acc+G; LSTM; c,h out.
// MODE 2: final: write d_out (NCHW f32).
// ---------------------------------------------------------------------------
template <int MODE>
__launch_bounds__(256, 2)
__global__ void conv4(const u16* __restrict__ inA, const u16* __restrict__ inH,
                      const u16* __restrict__ wW, const u16* __restrict__ wU,
                      const float* __restrict__ bWi, const float* __restrict__ bUi,
                      const float* __restrict__ bWf, const float* __restrict__ bUf,
                      const float* __restrict__ bWo, const float* __restrict__ bUo,
                      const float* __restrict__ bWc, const float* __restrict__ bUc,
                      float* __restrict__ G, const float* __restrict__ c_src,
                      float* __restrict__ c_dst, u16* __restrict__ h_out,
                      float* __restrict__ out) {
  __shared__ __align__(16) u16 Alds[9 * 64 * 32];   // [k9][gch][ci]  36864 B
  __shared__ __align__(16) u16 Blds[10 * 18 * 32];  // [r][xx][ci]    11520 B
  const int tid = threadIdx.x;
  const int chgrp = blockIdx.x & 31;
  const int nhalf = (blockIdx.x >> 5) & 1;
  const int b = blockIdx.x >> 6;
  const int wave = tid >> 6, lane = tid & 63;
  const int row = lane & 15, quad = lane >> 4;
  const int NCH = (MODE == 0) ? 32 : 16;
  const int gyBase = nhalf * 8 - 1;   // global input row of Blds row 0

  // Zero Blds once (borders persist; DMA overwrites interior rows only).
  {
    i32x4 z = {0, 0, 0, 0};
    i32x4* bz = (i32x4*)Blds;
#pragma unroll
    for (int i = 0; i < 6; ++i) {
      int k = tid + 256 * i;
      if (k < 1440) bz[k] = z;
    }
  }
  __syncthreads();  // zeroing must complete before stage(0)'s DMA lands

  const u16* wsrcW = wW + (size_t)chgrp * 294912;
  const u16* wsrcU = wU + (size_t)chgrp * 294912;
  const u16* isrcA = inA + (size_t)b * 131072;
  const u16* isrcH = inH + (size_t)b * 131072;

  auto stage = [&](int k) {
    const u16* gw;
    const u16* gi;
    if (MODE == 0 && k < 16) { gw = wsrcW + k * 18432; gi = isrcA + k * 32; }
    else                     { gw = wsrcU + (k & 15) * 18432; gi = isrcH + (k & 15) * 32; }
    // weights: 9 wave-level 1 KB DMAs per wave, fully contiguous 36864 B
#pragma unroll
    for (int i = 0; i < 9; ++i)
      gl16(gw + (i * 256 + tid) * 8, &Alds[(i * 256 + wave * 64) * 8]);
    // input rows: Blds row r <- global row gyBase+r; 4 lanes x 16B per position
#pragma unroll
    for (int j = 0; j < 3; ++j) {
      int r = j * 4 + wave;
      int gy = gyBase + r;
      if (r < 10 && gy >= 0 && gy < 16)
        gl16(gi + (size_t)(gy * 16 + (lane >> 2)) * 512 + (lane & 3) * 8,
             &Blds[r * 576 + 32]);
    }
  };

  f32x4 acc[4][2];
#pragma unroll
  for (int m = 0; m < 4; ++m)
#pragma unroll
    for (int n = 0; n < 2; ++n) acc[m][n] = (f32x4){0.f, 0.f, 0.f, 0.f};

  const int ch0 = chgrp * 16 + quad * 4;
  float* gptr = G + (size_t)blockIdx.x * 8192 + wave * 2048 + lane * 4;

  stage(0);
  __syncthreads();  // barrier drains DMA (vmcnt0) -> chunk 0 ready

#pragma unroll 1
  for (int k = 0; k < NCH; ++k) {
#pragma unroll
    for (int kx = 0; kx < 3; ++kx) {
      f16x8 bfr[4];  // input rows wave*2 .. wave*2+3 (shared across ky,n)
#pragma unroll
      for (int jj = 0; jj < 4; ++jj)
        bfr[jj] = *(const f16x8*)(&Blds[(wave * 2 + jj) * 576 + (row + kx) * 32 + quad * 8]);
#pragma unroll
      for (int ky = 0; ky < 3; ++ky) {
#pragma unroll
        for (int m = 0; m < 4; ++m) {
          f16x8 af = *(const f16x8*)(&Alds[((ky * 3 + kx) * 64 + m * 16 + row) * 32 + quad * 8]);
#pragma unroll
          for (int n = 0; n < 2; ++n)
            acc[m][n] = __builtin_amdgcn_mfma_f32_16x16x32_f16(af, bfr[n + ky], acc[m][n], 0, 0, 0);
        }
      }
    }
    if constexpr (MODE == 0) {
      if (k == 15) {  // W-half done: add biases, persist G = conv(AM,W)+bW+bU
#pragma unroll
        for (int m = 0; m < 4; ++m) {
          const float* bw = m == 0 ? bWi : m == 1 ? bWf : m == 2 ? bWo : bWc;
          const float* bu = m == 0 ? bUi : m == 1 ? bUf : m == 2 ? bUo : bUc;
          f32x4 bias;
#pragma unroll
          for (int r = 0; r < 4; ++r) bias[r] = bw[ch0 + r] + bu[ch0 + r];
#pragma unroll
          for (int n = 0; n < 2; ++n) {
            acc[m][n] = acc[m][n] + bias;
            *(f32x4*)(gptr + (m * 2 + n) * 256) = acc[m][n];
          }
        }
      }
    }
    if (k + 1 < NCH) {
      __syncthreads();   // all waves done reading LDS for chunk k
      stage(k + 1);
      __syncthreads();   // barrier drains DMA -> chunk k+1 ready
    }
  }

  // ---- epilogue: LSTM update ----
#pragma unroll
  for (int n = 0; n < 2; ++n) {
    const int p = (nhalf * 8 + wave * 2 + n) * 16 + row;
    f32x4 zi = acc[0][n], zf = acc[1][n], zo = acc[2][n], zg = acc[3][n];
    if constexpr (MODE != 0) {
      zi = zi + *(const f32x4*)(gptr + (0 + n) * 256);
      zf = zf + *(const f32x4*)(gptr + (2 + n) * 256);
      zo = zo + *(const f32x4*)(gptr + (4 + n) * 256);
      zg = zg + *(const f32x4*)(gptr + (6 + n) * 256);
    }
    f32x4 cold;
#pragma unroll
    for (int r = 0; r < 4; ++r)
      cold[r] = c_src[(size_t)(b * 512 + ch0 + r) * 256 + p];
    f32x4 cnew, hv;
#pragma unroll
    for (int r = 0; r < 4; ++r) {
      float iv = sigm(zi[r]);
      float fv = sigm(zf[r]);
      float ov = sigm(zo[r]);
      float gv = tanh_(zg[r]);
      float cn = fmaf(gv, iv, fv * cold[r]);
      cnew[r] = cn;
      hv[r] = tanh_(cn) * ov;
    }
    if constexpr (MODE != 2) {
#pragma unroll
      for (int r = 0; r < 4; ++r)
        c_dst[(size_t)(b * 512 + ch0 + r) * 256 + p] = cnew[r];
      us4 hb;
      hb[0] = f2h(hv[0]); hb[1] = f2h(hv[1]);
      hb[2] = f2h(hv[2]); hb[3] = f2h(hv[3]);
      *(us4*)(h_out + (size_t)b * 131072 + (size_t)p * 512 + ch0) = hb;
    } else {
#pragma unroll
      for (int r = 0; r < 4; ++r)
        out[(size_t)(b * 512 + ch0 + r) * 256 + p] = hv[r];
    }
  }
}

extern "C" void kernel_launch(void* const* d_in, const int* in_sizes, int n_in,
                              void* d_out, int out_size, void* d_ws, size_t ws_size,
                              hipStream_t stream) {
  const float* x    = (const float*)d_in[0];
  const float* txt  = (const float*)d_in[1];
  const float* Wi_w = (const float*)d_in[7];
  const float* Wi_b = (const float*)d_in[8];
  const float* Ui_w = (const float*)d_in[9];
  const float* Ui_b = (const float*)d_in[10];
  const float* Wf_w = (const float*)d_in[11];
  const float* Wf_b = (const float*)d_in[12];
  const float* Uf_w = (const float*)d_in[13];
  const float* Uf_b = (const float*)d_in[14];
  const float* Wc_w = (const float*)d_in[15];
  const float* Wc_b = (const float*)d_in[16];
  const float* Uc_w = (const float*)d_in[17];
  const float* Uc_b = (const float*)d_in[18];
  const float* Wo_w = (const float*)d_in[19];
  const float* Wo_b = (const float*)d_in[20];
  const float* Uo_w = (const float*)d_in[21];
  const float* Uo_b = (const float*)d_in[22];
  const float* WQ   = (const float*)d_in[23];
  const float* WK   = (const float*)d_in[24];
  const float* WV   = (const float*)d_in[25];
  const float* Wsw  = (const float*)d_in[26];
  const float* Wsb  = (const float*)d_in[27];
  (void)in_sizes; (void)n_in; (void)ws_size;

  char* ws = (char*)d_ws;
  size_t off = 0;
  auto carve = [&](size_t n) {
    char* p = ws + off;
    off += (n + 255) & ~(size_t)255;
    return p;
  };
  u16* WswzW    = (u16*)carve(18874368);   // 4x512x512x9 fp16, swizzled
  u16* WswzU    = (u16*)carve(18874368);
  u16* AM       = (u16*)carve(2097152);    // fp16 NHWC
  u16* H0       = (u16*)carve(2097152);
  u16* H1       = (u16*)carve(2097152);
  float* G      = (float*)carve(16777216); // fragment-layout W-conv + biases
  float* C      = (float*)carve(4194304);  // cell state, NCHW f32
  float* scores = (float*)carve(8192);     // [8 b][256 p]
  float* sb     = (float*)carve(256);      // s, b0

  hipMemsetAsync(scores, 0, 8192, stream);  // scores accumulated via atomicAdd

  prep_big<<<3072, 256, 0, stream>>>(WQ, WK, txt, WV, Wsw, Wsb,
                                     Wi_w, Wf_w, Wo_w, Wc_w,
                                     Ui_w, Uf_w, Uo_w, Uc_w,
                                     WswzW, WswzU, scores, sb);
  prep_inputs<<<4096, 256, 0, stream>>>(x, scores, sb, AM, H0);

  // t=0 fused (W on AM + U on H0), then 3 more timesteps ping-ponging h.
  conv4<0><<<512, 256, 0, stream>>>(AM, H0, WswzW, WswzU,
                                    Wi_b, Ui_b, Wf_b, Uf_b, Wo_b, Uo_b, Wc_b, Uc_b,
                                    G, x, C, H1, nullptr);
  conv4<1><<<512, 256, 0, stream>>>(nullptr, H1, nullptr, WswzU,
                                    nullptr, nullptr, nullptr, nullptr,
                                    nullptr, nullptr, nullptr, nullptr,
                                    G, C, C, H0, nullptr);
  conv4<1><<<512, 256, 0, stream>>>(nullptr, H0, nullptr, WswzU,
                                    nullptr, nullptr, nullptr, nullptr,
                                    nullptr, nullptr, nullptr, nullptr,
                                    G, C, C, H1, nullptr);
  conv4<2><<<512, 256, 0, stream>>>(nullptr, H1, nullptr, WswzU,
                                    nullptr, nullptr, nullptr, nullptr,
                                    nullptr, nullptr, nullptr, nullptr,
                                    G, C, nullptr, nullptr, (float*)d_out);
}